// Round 2
// baseline (821.513 us; speedup 1.0000x reference)
//
#include <hip/hip_runtime.h>

// GAT fused kernel for MI355X (gfx950).
// B=32768 graphs, N=14 nodes, F=C=128, E=64 edges (+14 self loops).
// Inputs FLOAT32 (edge_list int32) -- round-1 NaN traced to misreading f32 as
// bf16 pairs (low halves ~1e8 -> exp overflow -> inf/inf = NaN).
// Output float32: pred[32768] ++ attn[32768*196].
//
// Design:
//  - setup_kernel: w_eff = Wl @ Wp (f32, 1792) + b_eff into d_ws (no
//    nonlinearity between Wl and Wp in the reference -> compose once).
//  - gat_kernel: 512 threads = 8 waves, wave-per-graph. W1^T/W2^T converted to
//    bf16 and staged once per block in LDS (stride 136: 16B-aligned b128 frag
//    reads, 2-way-max bank aliasing = free). Per-wave private scratch; single
//    __syncthreads after staging, then wave-internal __threadfence_block()
//    fences only (wave64 lockstep; fences emit s_waitcnt lgkmcnt(0)).
//  - h = x@W via mfma_f32_16x16x32_bf16 (A: m=lane&15,k=quad*8+j; B: n=lane&15,
//    k=quad*8+j; C/D: col=lane&15,row=quad*4+reg -- guide-verified layouts).
//  - Edge softmax without max-shift (logits O(1), exp safe in f32).
//  - Aggregation as dense P[dst][src] (duplicates summed via LDS atomicAdd,
//    matching reference scatter-add) then out = P@h via same MFMA shape, K=32
//    with quads>=2 contributing zero fragments.

#define NEG_SLOPE 0.2f

typedef __bf16 bf16x8 __attribute__((ext_vector_type(8)));
typedef float f32x4 __attribute__((ext_vector_type(4)));
typedef unsigned short us4v __attribute__((ext_vector_type(4)));
typedef unsigned short us8v __attribute__((ext_vector_type(8)));

static __device__ __forceinline__ unsigned short f2bf(float f) {
  unsigned u = __builtin_bit_cast(unsigned, f);
  return (unsigned short)((u + 0x7FFFu + ((u >> 16) & 1u)) >> 16); // RNE, finite inputs
}

// ---------- setup: w_eff[r] = sum_c Wl[r][c]*Wp[c]; w_eff[1792] = bl@Wp + bp ----------
__global__ void gat_setup_kernel(const float* __restrict__ Wl,
                                 const float* __restrict__ bl,
                                 const float* __restrict__ Wp,
                                 const float* __restrict__ bp,
                                 float* __restrict__ weff) {
  int tid = threadIdx.x; // 256 threads, 1 block
  for (int r = tid; r < 1792; r += 256) {
    float s = 0.f;
    #pragma unroll 8
    for (int c = 0; c < 64; ++c) s += Wl[r * 64 + c] * Wp[c];
    weff[r] = s;
  }
  if (tid == 0) {
    float s = 0.f;
    for (int c = 0; c < 64; ++c) s += bl[c] * Wp[c];
    weff[1792] = s + bp[0];
  }
}

// Per-wave (per-graph) LDS scratch. sizeof = 9424 (16B multiple).
struct __align__(16) WaveLds {
  unsigned short xh[3072]; // union: xg[16][136] (layer input, A-op) / ht[128][24] (h^T, B-op of P@h)
  unsigned short Pb[384];  // P bf16 [16][24] (A-op of P@h)
  float Pf[224];           // P f32 [14][16], [dst][src], atomicAdd target
  float earr[80];          // exp(leaky(logit)) per edge (78 used)
  int sd[80];              // (src<<8)|dst per edge
  float asn[16];           // per-node src score
  float adn[16];           // per-node dst score
  float mz[16];            // 1/z per dst node
  float attn[196];         // [src][dst] f32, layer-2 alpha
};

__global__ __launch_bounds__(512, 2) void gat_kernel(
    const float* __restrict__ feat, const int* __restrict__ edges,
    const float* __restrict__ W1, const float* __restrict__ as1v,
    const float* __restrict__ ad1v, const float* __restrict__ b1v,
    const float* __restrict__ W2, const float* __restrict__ as2v,
    const float* __restrict__ ad2v, const float* __restrict__ b2v,
    const float* __restrict__ weff, float* __restrict__ out) {
  __shared__ unsigned short sWt[2][128 * 136]; // W^T bf16: sWt[l][n*136+k] = W[k][n]
  __shared__ float sweff[1792];
  __shared__ float svec[6][128]; // as1, ad1, b1, as2, ad2, b2
  __shared__ WaveLds wls[8];

  const int tid = threadIdx.x;
  const int wave = tid >> 6, lane = tid & 63;
  const int q = lane >> 4, l = lane & 15;
  const float beff = weff[1792];

  // ---- block staging (single __syncthreads in the whole kernel) ----
  for (int w = 0; w < 2; ++w) {
    const float* W = w ? W2 : W1;
    unsigned short* dst0 = &sWt[w][0];
    for (int idx = tid * 4; idx < 16384; idx += 2048) { // 8 iters, f32x4 coalesced
      f32x4 v = *(const f32x4*)(W + idx);
      int k = idx >> 7, n = idx & 127;
      dst0[(n + 0) * 136 + k] = f2bf(v[0]);
      dst0[(n + 1) * 136 + k] = f2bf(v[1]);
      dst0[(n + 2) * 136 + k] = f2bf(v[2]);
      dst0[(n + 3) * 136 + k] = f2bf(v[3]);
    }
  }
  for (int idx = tid; idx < 1792; idx += 512) sweff[idx] = weff[idx];
  if (tid < 128) {
    svec[0][tid] = as1v[tid]; svec[1][tid] = ad1v[tid]; svec[2][tid] = b1v[tid];
    svec[3][tid] = as2v[tid]; svec[4][tid] = ad2v[tid]; svec[5][tid] = b2v[tid];
  }
  __syncthreads();

  const int g = blockIdx.x * 8 + wave;
  WaveLds& S = wls[wave];

  // ---- stage feature (f32 -> bf16) -> xg[16][136]; zero rows 14..15 ----
  {
    const float* fb = feat + (size_t)g * 1792;
    for (int i = lane; i < 448; i += 64) { // 448 f32x4 groups, coalesced 16B/lane
      f32x4 v = *(const f32x4*)(fb + i * 4);
      us4v hv;
      hv[0] = f2bf(v[0]); hv[1] = f2bf(v[1]); hv[2] = f2bf(v[2]); hv[3] = f2bf(v[3]);
      int row = i >> 5, col = (i & 31) << 2;
      *(us4v*)(&S.xh[row * 136 + col]) = hv;
    }
    if (lane < 32) {
      int row = 14 + (lane >> 4), c8 = (lane & 15) << 3;
      us8v z8 = {0, 0, 0, 0, 0, 0, 0, 0};
      *(us8v*)(&S.xh[row * 136 + c8]) = z8;
    }
  }
  // edge list into regs (one edge per lane; E=64 exactly)
  int esrc, edst;
  {
    const int2 e2 = *(const int2*)(edges + (size_t)g * 128 + lane * 2);
    esrc = e2.x; edst = e2.y;
  }
  __threadfence_block();

  us8v z8v = {0, 0, 0, 0, 0, 0, 0, 0};
  const bf16x8 zf = __builtin_bit_cast(bf16x8, z8v);
  f32x4 oacc[8];

  for (int lr = 0; lr < 2; ++lr) {
    const unsigned short* wt = sWt[lr];
    const float* asv = svec[lr * 3 + 0];
    const float* adv = svec[lr * 3 + 1];
    const float* bsv = svec[lr * 3 + 2];

    // ---- h = x @ W  (M=16, N=128 in 8 tiles, K=128 in 4 steps) ----
    f32x4 hacc[8];
    #pragma unroll
    for (int t = 0; t < 8; ++t) hacc[t] = (f32x4){0.f, 0.f, 0.f, 0.f};
    #pragma unroll
    for (int ks = 0; ks < 4; ++ks) {
      bf16x8 af = *(const bf16x8*)(&S.xh[l * 136 + ks * 32 + q * 8]); // A[m=l][k=8q+j]
      #pragma unroll
      for (int t = 0; t < 8; ++t) {
        bf16x8 bfv = *(const bf16x8*)(&wt[(t * 16 + l) * 136 + ks * 32 + q * 8]); // B[k][n=16t+l]
        hacc[t] = __builtin_amdgcn_mfma_f32_16x16x32_bf16(af, bfv, hacc[t], 0, 0, 0);
      }
    }

    // ---- scores as/ad: partial over cols (f32), butterfly over l ----
    f32x4 pas = {0.f, 0.f, 0.f, 0.f}, padv = {0.f, 0.f, 0.f, 0.f};
    #pragma unroll
    for (int t = 0; t < 8; ++t) {
      float ca = asv[t * 16 + l], cd = adv[t * 16 + l];
      pas += hacc[t] * ca;
      padv += hacc[t] * cd;
    }
    #pragma unroll
    for (int m = 1; m <= 8; m <<= 1) {
      #pragma unroll
      for (int r = 0; r < 4; ++r) {
        pas[r] += __shfl_xor(pas[r], m, 64);
        padv[r] += __shfl_xor(padv[r], m, 64);
      }
    }
    if (l == 0) {
      #pragma unroll
      for (int r = 0; r < 4; ++r) { S.asn[4 * q + r] = pas[r]; S.adn[4 * q + r] = padv[r]; }
    }

    // ---- h -> ht[128][24] bf16 (h^T; B-operand of P@h); h rows 14/15 are cols here ----
    #pragma unroll
    for (int t = 0; t < 8; ++t) {
      us4v hv;
      hv[0] = f2bf(hacc[t][0]); hv[1] = f2bf(hacc[t][1]);
      hv[2] = f2bf(hacc[t][2]); hv[3] = f2bf(hacc[t][3]);
      *(us4v*)(&S.xh[(t * 16 + l) * 24 + q * 4]) = hv; // ht[c=16t+l][node=4q+r]
    }
    __threadfence_block();

    // ---- edges: ev = exp(leaky(asn[src]+adn[dst])); no max-shift needed ----
    float ev, ev2 = 0.f;
    {
      float f = S.asn[esrc] + S.adn[edst];
      ev = __expf(f > 0.f ? f : NEG_SLOPE * f);
      S.earr[lane] = ev;
      S.sd[lane] = (esrc << 8) | edst;
      if (lane < 14) { // self loops, edges 64..77
        float f2 = S.asn[lane] + S.adn[lane];
        ev2 = __expf(f2 > 0.f ? f2 : NEG_SLOPE * f2);
        S.earr[64 + lane] = ev2;
        S.sd[64 + lane] = (lane << 8) | lane;
      }
    }
    for (int i = lane; i < 224; i += 64) S.Pf[i] = 0.f;
    if (lr) {
      for (int i = lane; i < 196; i += 64) S.attn[i] = 0.f;
    }
    __threadfence_block();

    // ---- per-dst denominator (broadcast LDS scans, lanes 0..13) ----
    if (lane < 14) {
      float z = 0.f;
      for (int e = 0; e < 78; ++e)
        if ((S.sd[e] & 255) == lane) z += S.earr[e];
      S.mz[lane] = 1.f / z;
    }
    __threadfence_block();

    // ---- alpha; P[dst][src] (duplicates sum); layer-2 attn[src][dst] = alpha ----
    {
      float a = ev * S.mz[edst];
      atomicAdd(&S.Pf[edst * 16 + esrc], a);
      if (lr) S.attn[esrc * 14 + edst] = a; // duplicate edges write identical bits
      if (lane < 14) {
        float a2 = ev2 * S.mz[lane];
        atomicAdd(&S.Pf[lane * 16 + lane], a2);
        if (lr) S.attn[lane * 14 + lane] = a2;
      }
    }
    __threadfence_block();

    // ---- Pf -> Pb bf16 [16][24]; rows/cols >=14 zeroed ----
    for (int i = lane; i < 256; i += 64) {
      int r = i >> 4, c = i & 15;
      S.Pb[r * 24 + c] = (r < 14 && c < 14) ? f2bf(S.Pf[r * 16 + c]) : (unsigned short)0;
    }
    __threadfence_block();

    // ---- out = P @ h + b  (K=32; quads>=2 feed zero frags, K-extent is 16) ----
    #pragma unroll
    for (int t = 0; t < 8; ++t) {
      float bb = bsv[t * 16 + l];
      oacc[t] = (f32x4){bb, bb, bb, bb};
    }
    bf16x8 paf = (q < 2) ? *(const bf16x8*)(&S.Pb[l * 24 + q * 8]) : zf;
    #pragma unroll
    for (int t = 0; t < 8; ++t) {
      bf16x8 hbf = (q < 2) ? *(const bf16x8*)(&S.xh[(t * 16 + l) * 24 + q * 8]) : zf;
      oacc[t] = __builtin_amdgcn_mfma_f32_16x16x32_bf16(paf, hbf, oacc[t], 0, 0, 0);
    }

    if (lr == 0) {
      // x2 = relu(out1) -> xg for layer 2; rows 14/15 = relu(b1 + 0) = 0 (b1 == 0)
      __threadfence_block();
      #pragma unroll
      for (int t = 0; t < 8; ++t) {
        #pragma unroll
        for (int r = 0; r < 4; ++r) {
          float v = fmaxf(oacc[t][r], 0.f);
          S.xh[(4 * q + r) * 136 + t * 16 + l] = f2bf(v);
        }
      }
      __threadfence_block();
    }
  }

  // ---- pred = sigmoid(dot(h2flat, w_eff) + b_eff), rows 0..13 only ----
  float part = 0.f;
  #pragma unroll
  for (int t = 0; t < 8; ++t) {
    #pragma unroll
    for (int r = 0; r < 4; ++r) {
      int row = 4 * q + r;
      if (row < 14) part += oacc[t][r] * sweff[row * 128 + t * 16 + l];
    }
  }
  #pragma unroll
  for (int m = 1; m < 64; m <<= 1) part += __shfl_xor(part, m, 64);
  if (lane == 0) {
    float p = 1.f / (1.f + __expf(-(part + beff)));
    out[g] = p;
  }

  // ---- attn out: 196 f32 per graph ----
  {
    float* oa = out + 32768 + (size_t)g * 196;
    for (int i = lane; i < 196; i += 64) oa[i] = S.attn[i];
  }
}

extern "C" void kernel_launch(void* const* d_in, const int* in_sizes, int n_in,
                              void* d_out, int out_size, void* d_ws, size_t ws_size,
                              hipStream_t stream) {
  const float* feat = (const float*)d_in[0];
  const int* edges = (const int*)d_in[1];
  const float* W1 = (const float*)d_in[2];
  const float* as1 = (const float*)d_in[3];
  const float* ad1 = (const float*)d_in[4];
  const float* b1 = (const float*)d_in[5];
  const float* W2 = (const float*)d_in[6];
  const float* as2 = (const float*)d_in[7];
  const float* ad2 = (const float*)d_in[8];
  const float* b2 = (const float*)d_in[9];
  const float* Wl = (const float*)d_in[10];
  const float* bl = (const float*)d_in[11];
  const float* Wp = (const float*)d_in[12];
  const float* bp = (const float*)d_in[13];
  float* weff = (float*)d_ws; // 1793 f32, rewritten every call

  gat_setup_kernel<<<1, 256, 0, stream>>>(Wl, bl, Wp, bp, weff);
  gat_kernel<<<4096, 512, 0, stream>>>(feat, edges, W1, as1, ad1, b1,
                                       W2, as2, ad2, b2, weff,
                                       (float*)d_out);
}

// Round 3
// 482.617 us; speedup vs baseline: 1.7022x; 1.7022x over previous
//
#include <hip/hip_runtime.h>

// GAT fused kernel for MI355X (gfx950) -- round 3.
// B=32768 graphs, N=14 nodes, F=C=128, E=64 edges (+14 self loops).
// Inputs f32 (edge_list int32); output f32: pred[32768] ++ attn[32768*196].
//
// Round-2 post-mortem: 556us, latency-bound (Occ 23%, VALU 16%, MFMA 3%,
// 7.7e7 LDS bank-conflict cycles). Fixes this round:
//  1. Per-dst softmax denominator: 78-iter serial LDS scan (≈18k cyc/layer,
//     14/64 lanes) -> atomicAdd unnormalized P, then 16-lane row-sums.
//  2. W1/W2 no longer staged per block (16-way-conflict writes, 70KB LDS):
//     setup kernel emits bf16 MFMA B-fragments in wave-load order to d_ws;
//     main kernel loads them 16B/lane coalesced from L2 (64KB resident).
//  3. Layer-1 A-fragments straight from global feature (skip LDS round-trip).
//  4. LDS = 4 x 8912B (wave-private) = 35.6KB/block @ 256 thr -> 4 blocks/CU,
//     16 waves/CU; no __syncthreads anywhere; wave-internal fences only.
//  5. Wl@Wp composed (no nonlinearity between) into C-frag-ordered weffc.

#define NEG_SLOPE 0.2f

typedef __bf16 bf16x8 __attribute__((ext_vector_type(8)));
typedef float f32x4 __attribute__((ext_vector_type(4)));
typedef unsigned short us4v __attribute__((ext_vector_type(4)));
typedef unsigned short us8v __attribute__((ext_vector_type(8)));

static __device__ __forceinline__ unsigned short f2bf(float f) {
  unsigned u = __builtin_bit_cast(unsigned, f);
  return (unsigned short)((u + 0x7FFFu + ((u >> 16) & 1u)) >> 16); // RNE, finite
}

// ---------------- setup: W frags (bf16, wave-load order) + weffc ----------------
// wfrag short offset: (((lr*4+ks)*8+t)*64 + lane)*8 ; element j = W[ks*32+q*8+j][t*16+l]
// weffc[(t*64+lane)*4+r] = (4q+r)<14 ? sum_c Wl[((4q+r)*128+t*16+l)*64+c]*Wp[c] : 0
__global__ void gat_setup_kernel(const float* __restrict__ W1, const float* __restrict__ W2,
                                 const float* __restrict__ Wl, const float* __restrict__ bl,
                                 const float* __restrict__ Wp, const float* __restrict__ bp,
                                 unsigned short* __restrict__ wfrag, float* __restrict__ weffc) {
  const int blk = blockIdx.x, tid = threadIdx.x; // 17 blocks x 256
  if (blk < 16) {
    int slot = blk * 256 + tid; // (lr,ks,t,lane)
    int lane = slot & 63, t = (slot >> 6) & 7, ks = (slot >> 9) & 3, lr = slot >> 11;
    const float* W = lr ? W2 : W1;
    int q = lane >> 4, l = lane & 15;
    int n = t * 16 + l, k0 = ks * 32 + q * 8;
    us8v hv;
    #pragma unroll
    for (int j = 0; j < 8; ++j) hv[j] = f2bf(W[(k0 + j) * 128 + n]);
    *(us8v*)(wfrag + slot * 8) = hv;
  } else {
    for (int i = tid; i < 2048; i += 256) {
      int r = i & 3, lane = (i >> 2) & 63, t = i >> 8;
      int q = lane >> 4, l = lane & 15;
      int row = 4 * q + r, col = t * 16 + l;
      float s = 0.f;
      if (row < 14) {
        const float* wl = Wl + (size_t)(row * 128 + col) * 64;
        #pragma unroll 8
        for (int c = 0; c < 64; ++c) s += wl[c] * Wp[c];
      }
      weffc[i] = s;
    }
    if (tid == 0) {
      float s = 0.f;
      for (int c = 0; c < 64; ++c) s += bl[c] * Wp[c];
      weffc[2048] = s + bp[0];
    }
  }
}

// Wave-private LDS scratch, 8912 B.
struct __align__(16) WaveLds {
  unsigned short xh[3072]; // xg[16][136] (layer-2 A-op) / ht[128][24] (P@h B-op)
  unsigned short Pb[384];  // bf16 P [16][24] (P@h A-op)
  float Pf[256];           // unnormalized P f32 [16][16] [dst][src] (atomicAdd)
  float asn[16], adn[16], mz[16];
  float attn[196];         // [src][dst] layer-2 alpha
};

__global__ __launch_bounds__(256, 4) void gat_kernel(
    const float* __restrict__ feat, const int* __restrict__ edges,
    const float* __restrict__ as1v, const float* __restrict__ ad1v,
    const float* __restrict__ b1v, const float* __restrict__ as2v,
    const float* __restrict__ ad2v, const float* __restrict__ b2v,
    const unsigned short* __restrict__ wfrag, const float* __restrict__ weffc,
    float* __restrict__ out) {
  __shared__ WaveLds wls[4];
  const int tid = threadIdx.x;
  const int wave = tid >> 6, lane = tid & 63;
  const int q = lane >> 4, l = lane & 15;
  const int g = blockIdx.x * 4 + wave;
  WaveLds& S = wls[wave];

  // edge endpoints, one edge per lane (E=64)
  int esrc, edst;
  { const int2 e2 = *(const int2*)(edges + (size_t)g * 128 + lane * 2); esrc = e2.x; edst = e2.y; }

  us8v z8v = {0, 0, 0, 0, 0, 0, 0, 0};
  const bf16x8 zf = __builtin_bit_cast(bf16x8, z8v);

  // layer-1 A-fragments straight from global feature; rows m=l>=14 are zero
  bf16x8 af1[4];
  if (l < 14) {
    const float* fb = feat + (size_t)g * 1792 + l * 128 + q * 8;
    #pragma unroll
    for (int ks = 0; ks < 4; ++ks) {
      f32x4 v0 = *(const f32x4*)(fb + ks * 32);
      f32x4 v1 = *(const f32x4*)(fb + ks * 32 + 4);
      us8v hv;
      hv[0] = f2bf(v0[0]); hv[1] = f2bf(v0[1]); hv[2] = f2bf(v0[2]); hv[3] = f2bf(v0[3]);
      hv[4] = f2bf(v1[0]); hv[5] = f2bf(v1[1]); hv[6] = f2bf(v1[2]); hv[7] = f2bf(v1[3]);
      af1[ks] = __builtin_bit_cast(bf16x8, hv);
    }
  } else {
    #pragma unroll
    for (int ks = 0; ks < 4; ++ks) af1[ks] = zf;
  }

  f32x4 oacc[8];

  for (int lr = 0; lr < 2; ++lr) {
    const float* asv = lr ? as2v : as1v;
    const float* adv = lr ? ad2v : ad1v;
    const float* bsv = lr ? b2v : b1v;
    const unsigned short* wfl = wfrag + lr * 16384;

    // ---- h = x @ W (M=16, N=128 in 8 tiles, K=128 in 4 steps); B-frags from L2 ----
    f32x4 hacc[8];
    #pragma unroll
    for (int t = 0; t < 8; ++t) hacc[t] = (f32x4){0.f, 0.f, 0.f, 0.f};
    #pragma unroll
    for (int ks = 0; ks < 4; ++ks) {
      bf16x8 af = lr ? *(const bf16x8*)(&S.xh[l * 136 + ks * 32 + q * 8]) : af1[ks];
      const unsigned short* wk = wfl + ks * 4096 + lane * 8;
      #pragma unroll
      for (int t = 0; t < 8; ++t) {
        bf16x8 bfv = *(const bf16x8*)(wk + t * 512); // 16B/lane, coalesced, L2-hot
        hacc[t] = __builtin_amdgcn_mfma_f32_16x16x32_bf16(af, bfv, hacc[t], 0, 0, 0);
      }
    }

    // ---- node scores: per-lane partial over cols, butterfly over l (no LDS) ----
    f32x4 pas = {0.f, 0.f, 0.f, 0.f}, padv = {0.f, 0.f, 0.f, 0.f};
    #pragma unroll
    for (int t = 0; t < 8; ++t) {
      float ca = asv[t * 16 + l], cd = adv[t * 16 + l]; // 512B arrays, L1-hot
      pas += hacc[t] * ca;
      padv += hacc[t] * cd;
    }
    #pragma unroll
    for (int m = 1; m <= 8; m <<= 1) {
      #pragma unroll
      for (int r = 0; r < 4; ++r) {
        pas[r] += __shfl_xor(pas[r], m, 64);
        padv[r] += __shfl_xor(padv[r], m, 64);
      }
    }
    if (l == 0) {
      #pragma unroll
      for (int r = 0; r < 4; ++r) { S.asn[4 * q + r] = pas[r]; S.adn[4 * q + r] = padv[r]; }
    }

    // ---- h -> ht[128][24] bf16 (B-op of P@h): ht[col][node] ----
    #pragma unroll
    for (int t = 0; t < 8; ++t) {
      us4v hv;
      hv[0] = f2bf(hacc[t][0]); hv[1] = f2bf(hacc[t][1]);
      hv[2] = f2bf(hacc[t][2]); hv[3] = f2bf(hacc[t][3]);
      *(us4v*)(&S.xh[(t * 16 + l) * 24 + q * 4]) = hv;
    }
    *(f32x4*)(&S.Pf[lane * 4]) = (f32x4){0.f, 0.f, 0.f, 0.f};
    if (lr) { for (int i = lane; i < 196; i += 64) S.attn[i] = 0.f; }
    __threadfence_block();

    // ---- edges: ev = exp(leaky(asn[src]+adn[dst])); accumulate unnormalized P ----
    float ev, ev2 = 0.f;
    {
      float f = S.asn[esrc] + S.adn[edst];
      ev = __expf(f > 0.f ? f : NEG_SLOPE * f);
      atomicAdd(&S.Pf[edst * 16 + esrc], ev);
      if (lane < 14) { // self loops
        float f2 = S.asn[lane] + S.adn[lane];
        ev2 = __expf(f2 > 0.f ? f2 : NEG_SLOPE * f2);
        atomicAdd(&S.Pf[lane * 17], ev2);
      }
    }
    __threadfence_block();

    // ---- per-dst 1/z = 1/rowsum(Pf) (16 lanes, 4x f32x4 each) ----
    if (lane < 16) {
      f32x4 s0 = *(const f32x4*)(&S.Pf[lane * 16]) + *(const f32x4*)(&S.Pf[lane * 16 + 4]) +
                 *(const f32x4*)(&S.Pf[lane * 16 + 8]) + *(const f32x4*)(&S.Pf[lane * 16 + 12]);
      float z = s0[0] + s0[1] + s0[2] + s0[3];
      S.mz[lane] = (lane < 14) ? 1.f / z : 0.f;
    }
    __threadfence_block();

    // ---- Pb = bf16(Pf * mz[row]); layer-2 attn[src][dst] = per-edge alpha ----
    #pragma unroll
    for (int i = lane; i < 256; i += 64) {
      int r = i >> 4, c = i & 15;
      float pv = S.Pf[i] * S.mz[r];
      S.Pb[r * 24 + c] = (r < 14 && c < 14) ? f2bf(pv) : (unsigned short)0;
    }
    if (lr) {
      S.attn[esrc * 14 + edst] = ev * S.mz[edst]; // duplicates write identical bits
      if (lane < 14) S.attn[lane * 15] = ev2 * S.mz[lane];
    }
    __threadfence_block();

    // ---- out = P @ h + b (K=32; quads>=2 feed zero frags) ----
    #pragma unroll
    for (int t = 0; t < 8; ++t) {
      float bb = bsv[t * 16 + l];
      oacc[t] = (f32x4){bb, bb, bb, bb};
    }
    bf16x8 paf = (q < 2) ? *(const bf16x8*)(&S.Pb[l * 24 + q * 8]) : zf;
    #pragma unroll
    for (int t = 0; t < 8; ++t) {
      bf16x8 hbf = (q < 2) ? *(const bf16x8*)(&S.xh[(t * 16 + l) * 24 + q * 8]) : zf;
      oacc[t] = __builtin_amdgcn_mfma_f32_16x16x32_bf16(paf, hbf, oacc[t], 0, 0, 0);
    }

    if (lr == 0) {
      // x2 = relu(out1) -> xg[16][136] for layer-2 A-op
      __threadfence_block();
      #pragma unroll
      for (int t = 0; t < 8; ++t) {
        #pragma unroll
        for (int r = 0; r < 4; ++r) {
          float v = fmaxf(oacc[t][r], 0.f);
          S.xh[(4 * q + r) * 136 + t * 16 + l] = f2bf(v);
        }
      }
      __threadfence_block();
    }
  }

  // ---- pred = sigmoid(sum oacc .* weffc + beff); weffc pre-masked rows>=14 ----
  float part = 0.f;
  #pragma unroll
  for (int t = 0; t < 8; ++t) {
    f32x4 wv = *(const f32x4*)(weffc + t * 256 + lane * 4); // coalesced, L2-hot
    part += oacc[t][0] * wv[0] + oacc[t][1] * wv[1] + oacc[t][2] * wv[2] + oacc[t][3] * wv[3];
  }
  #pragma unroll
  for (int m = 1; m < 64; m <<= 1) part += __shfl_xor(part, m, 64);
  if (lane == 0) {
    float p = 1.f / (1.f + __expf(-(part + weffc[2048])));
    out[g] = p;
  }

  // ---- attn out: 196 f32 per graph ----
  {
    float* oa = out + 32768 + (size_t)g * 196;
    for (int i = lane; i < 196; i += 64) oa[i] = S.attn[i];
  }
}

extern "C" void kernel_launch(void* const* d_in, const int* in_sizes, int n_in,
                              void* d_out, int out_size, void* d_ws, size_t ws_size,
                              hipStream_t stream) {
  const float* feat = (const float*)d_in[0];
  const int* edges = (const int*)d_in[1];
  const float* W1 = (const float*)d_in[2];
  const float* as1 = (const float*)d_in[3];
  const float* ad1 = (const float*)d_in[4];
  const float* b1 = (const float*)d_in[5];
  const float* W2 = (const float*)d_in[6];
  const float* as2 = (const float*)d_in[7];
  const float* ad2 = (const float*)d_in[8];
  const float* b2 = (const float*)d_in[9];
  const float* Wl = (const float*)d_in[10];
  const float* bl = (const float*)d_in[11];
  const float* Wp = (const float*)d_in[12];
  const float* bp = (const float*)d_in[13];

  unsigned short* wfrag = (unsigned short*)d_ws;          // 65536 B
  float* weffc = (float*)((char*)d_ws + 65536);           // 2049 f32

  gat_setup_kernel<<<17, 256, 0, stream>>>(W1, W2, Wl, bl, Wp, bp, wfrag, weffc);
  gat_kernel<<<8192, 256, 0, stream>>>(feat, edges, as1, ad1, b1, as2, ad2, b2,
                                       wfrag, weffc, (float*)d_out);
}